// Round 15
// baseline (375.333 us; speedup 1.0000x reference)
//
#include <hip/hip_runtime.h>
#include <cstdint>
#include <cstddef>

// MEASUREMENT ROUND: identical pipeline to round-10 (verified, absmax 0.03125),
// but k_prep body repeated x12 and k_fused body x8 (idempotent) so both kernels
// exceed the ~43us fill threshold and appear in rocprof top-5 with counters.
// True per-kernel cost = reported duration / reps.

using shortx8 = __attribute__((ext_vector_type(8))) short;
using floatx4 = __attribute__((ext_vector_type(4))) float;

__device__ __forceinline__ unsigned short f2b(float f) {
    union { float f; unsigned int i; } v; v.f = f;
    unsigned int x = v.i;
    return (unsigned short)((x + 0x7FFFu + ((x >> 16) & 1u)) >> 16); // RNE
}
__device__ __forceinline__ void gl_lds16(const unsigned short* g, unsigned short* l) {
    __builtin_amdgcn_global_load_lds(
        (const __attribute__((address_space(1))) unsigned int*)g,
        (__attribute__((address_space(3))) unsigned int*)l, 16, 0, 0);
}

// ---------- prep: gt [0,4224) + adj [4224,4736) + ftb [4736,6784) + wb {6784} ----------
__global__ void k_prep(const float* __restrict__ fc, const float* __restrict__ mask,
                       const float* __restrict__ adj, const float* __restrict__ ft,
                       const float* __restrict__ W,
                       unsigned short* __restrict__ gt, unsigned short* __restrict__ adjb,
                       unsigned short* __restrict__ ftb, unsigned short* __restrict__ wb) {
    const int tid = threadIdx.x;
    __shared__ float wls[32][33];
    __shared__ unsigned short tls[32][34];
    const int x = blockIdx.x;

    #pragma unroll 1
    for (int rep = 0; rep < 12; ++rep) {
        __syncthreads();
        asm volatile("" ::: "memory");   // defeat cross-rep load CSE (rule #17)

        if (x < 4224) {  // ---- gt ----
            const int jb = x % 132;
            const int rem = x / 132;
            const int nb = rem & 15, b = rem >> 4;
            const int n0 = nb * 32;
            const int r = tid >> 3, c4 = (tid & 7) * 4;
            if (jb >= 128) {
                const int t0 = (jb - 128) * 32;
                float4 mv = *(const float4*)(mask + ((size_t)b * 128 + t0 + r) * 512 + n0 + c4);
                ushort4 o;
                o.x = f2b(1.f - mv.x); o.y = f2b(1.f - mv.y);
                o.z = f2b(1.f - mv.z); o.w = f2b(1.f - mv.w);
                *(ushort4*)(gt + ((size_t)b * 4224 + 4096 + t0 + r) * 512 + n0 + c4) = o;
            } else {
                const int j0 = jb * 32;
                const int t0 = j0 & 127;
                {
                    float4 mv = *(const float4*)(mask + ((size_t)b * 128 + t0 + r) * 512 + n0 + c4);
                    wls[r][c4 + 0] = 1.f - mv.x; wls[r][c4 + 1] = 1.f - mv.y;
                    wls[r][c4 + 2] = 1.f - mv.z; wls[r][c4 + 3] = 1.f - mv.w;
                }
                float4 fv = *(const float4*)(fc + ((size_t)b * 512 + n0 + r) * 4096 + j0 + c4);
                __syncthreads();
                tls[c4 + 0][r] = f2b(fv.x * wls[c4 + 0][r]);
                tls[c4 + 1][r] = f2b(fv.y * wls[c4 + 1][r]);
                tls[c4 + 2][r] = f2b(fv.z * wls[c4 + 2][r]);
                tls[c4 + 3][r] = f2b(fv.w * wls[c4 + 3][r]);
                __syncthreads();
                ushort4 o;
                o.x = tls[r][c4 + 0]; o.y = tls[r][c4 + 1];
                o.z = tls[r][c4 + 2]; o.w = tls[r][c4 + 3];
                *(ushort4*)(gt + ((size_t)b * 4224 + j0 + r) * 512 + n0 + c4) = o;
            }
        } else if (x < 4736) {  // ---- adj ----
            int i4 = ((x - 4224) * 256 + tid) * 4;
            float4 v = *(const float4*)(adj + i4);
            ushort4 o;
            o.x = f2b(v.x); o.y = f2b(v.y); o.z = f2b(v.z); o.w = f2b(v.w);
            *(ushort4*)(adjb + i4) = o;
        } else if (x < 6784) {  // ---- ftb: [m][d][t] -> [m][t][d] bf16 ----
            const int fb = x - 4736;
            const int b = fb >> 10, rem = fb & 1023;
            const int m = rem >> 2, tb = rem & 3;
            const int r = tid >> 3, c4 = (tid & 7) * 4;
            float4 fv = *(const float4*)(ft + (((size_t)(b * 256 + m)) * 32 + r) * 128 + tb * 32 + c4);
            tls[c4 + 0][r] = f2b(fv.x); tls[c4 + 1][r] = f2b(fv.y);
            tls[c4 + 2][r] = f2b(fv.z); tls[c4 + 3][r] = f2b(fv.w);
            __syncthreads();
            ushort4 o;
            o.x = tls[r][c4 + 0]; o.y = tls[r][c4 + 1];
            o.z = tls[r][c4 + 2]; o.w = tls[r][c4 + 3];
            *(ushort4*)(ftb + (((size_t)(b * 256 + m)) * 128 + tb * 32 + r) * 32 + c4) = o;
        } else {  // ---- wb: fold W1+W2+W3, bf16 ----
            if (tid < 64) {
                for (int c = 0; c < 32; ++c) {
                    float w1 = W[tid * 96 + c];
                    float w2 = W[tid * 96 + 32 + c];
                    float w3 = W[tid * 96 + 64 + c];
                    wb[tid * 96 + c]      = f2b(w1 + w2 + w3);
                    wb[tid * 96 + 32 + c] = f2b(w2);
                    wb[tid * 96 + 64 + c] = f2b(w3);
                }
            }
        }
    }
}

// ---------- fused GEMM(2 orders + s) + MLP, grid (32, 8, 2), 256 thr ----------
__launch_bounds__(256, 2)
__global__ void k_fused(const unsigned short* __restrict__ adjb,
                        const unsigned short* __restrict__ gt,
                        const unsigned short* __restrict__ ftb,
                        const unsigned short* __restrict__ wb,
                        const float* __restrict__ bias, float* __restrict__ y) {
    const int jt = blockIdx.x, mt = blockIdx.y, b = blockIdx.z;
    const int t0 = jt * 4, m0 = mt * 32;
    const int tid = threadIdx.x;
    const int wave = tid >> 6, lane = tid & 63;
    const int l15 = lane & 15, quad = lane >> 4;
    const int wo = wave & 1, wj = wave >> 1;   // order-half, j-half
    const int srow = lane >> 3;                // 0..7 row in 8-row staging chunk
    const int ksw = (((lane & 7) ^ srow) * 8); // pre-swizzled k-offset (T2, rule #21)

    __shared__ __align__(16) unsigned short Al[2][2][32 * 64];  // [buf][ord] 16 KB
    __shared__ __align__(16) unsigned short Bl[2][144 * 64];    // 128 j + 16 s-dup, 36 KB
    __shared__ __align__(16) unsigned short Fl[128 * 32];       // ft tile [col][d], 8 KB
    __shared__ __align__(16) unsigned short Ul[2][128 * 32];    // u tiles [ord][col][d], 16 KB
    __shared__ float Rl[2 * 128];                               // 1/(s+1), 1 KB

    const unsigned short* gtb = gt + (size_t)b * 4224 * 512;

    // B tile-local row r -> gt row: j = (r&31)*128 + t0 + (r>>5)   (d=r&31, t=t0+(r>>5))
    #define STAGE(buf, k0)                                                            \
        _Pragma("unroll")                                                             \
        for (int aa = 0; aa < 2; ++aa) {                                              \
            const int a = wave * 2 + aa;           /* 0..7 */                         \
            const int ord = a >> 2, ch = a & 3;                                       \
            const int row = ch * 8 + srow;                                            \
            gl_lds16(adjb + ((size_t)((b * 2 + ord) * 256 + m0 + row)) * 512          \
                          + (k0) + ksw,                                               \
                     &Al[buf][ord][ch * 512]);                                        \
        }                                                                             \
        _Pragma("unroll")                                                             \
        for (int rr = 0; rr < 4; ++rr) {                                              \
            const int ch = wave * 4 + rr;          /* 0..15 */                        \
            const int row = ch * 8 + srow;                                            \
            const int jrow = (row & 31) * 128 + t0 + (row >> 5);                      \
            gl_lds16(gtb + (size_t)jrow * 512 + (k0) + ksw, &Bl[buf][ch * 512]);      \
        }                                                                             \
        if (wave < 2)                                                                 \
            gl_lds16(gtb + (size_t)(4096 + t0 + (srow & 3)) * 512 + (k0) + ksw,       \
                     &Bl[buf][128 * 64 + wave * 512]);

    #pragma unroll 1
    for (int rep = 0; rep < 8; ++rep) {
        __syncthreads();
        asm volatile("" ::: "memory");   // defeat cross-rep load CSE (rule #17)

        floatx4 acc[2][4], sacc[2];
        #pragma unroll
        for (int i = 0; i < 2; ++i) {
            sacc[i] = (floatx4){0.f, 0.f, 0.f, 0.f};
            #pragma unroll
            for (int j = 0; j < 4; ++j) acc[i][j] = (floatx4){0.f, 0.f, 0.f, 0.f};
        }

        STAGE(0, 0)
        // stage ft tile (swizzled source -> linear LDS); consumed after epilogue barrier
        #pragma unroll
        for (int cc = 0; cc < 2; ++cc) {
            const int c = wave * 2 + cc;               // 0..7
            const int col = c * 16 + (lane >> 2), qs = lane & 3;
            gl_lds16(ftb + (((size_t)(b * 256 + m0 + (col >> 2))) * 128 + t0 + (col & 3)) * 32
                         + ((qs ^ (col & 3)) * 8),
                     &Fl[c * 512]);
        }

        int cur = 0;
        for (int it = 0; it < 8; ++it) {
            __syncthreads();                  // buf[cur] ready (compiler drains vmcnt)
            if (it < 7) { STAGE(cur ^ 1, (it + 1) * 64) }
            #pragma unroll
            for (int ks = 0; ks < 2; ++ks) {
                const int swz = (((ks * 4 + quad) ^ (l15 & 7)) << 4);
                shortx8 af[2], bf[4];
                #pragma unroll
                for (int i = 0; i < 2; ++i)
                    af[i] = *(const shortx8*)((const char*)&Al[cur][wo][0]
                                              + (i * 16 + l15) * 128 + swz);
                #pragma unroll
                for (int jj = 0; jj < 4; ++jj)
                    bf[jj] = *(const shortx8*)((const char*)&Bl[cur][0]
                                               + (wj * 64 + jj * 16 + l15) * 128 + swz);
                #pragma unroll
                for (int i = 0; i < 2; ++i)
                    #pragma unroll
                    for (int jj = 0; jj < 4; ++jj)
                        acc[i][jj] = __builtin_amdgcn_mfma_f32_16x16x32_bf16(af[i], bf[jj],
                                                                             acc[i][jj], 0, 0, 0);
                if (wj == 0) {   // s-rows: every col a valid duplicate (t = t0 + (l15&3))
                    shortx8 sf = *(const shortx8*)((const char*)&Bl[cur][0]
                                                   + (128 + l15) * 128 + swz);
                    #pragma unroll
                    for (int i = 0; i < 2; ++i)
                        sacc[i] = __builtin_amdgcn_mfma_f32_16x16x32_bf16(af[i], sf,
                                                                          sacc[i], 0, 0, 0);
                }
            }
            cur ^= 1;
        }

        // ---- epilogue: load W frags (global, hides under LDS writes) ----
        shortx8 aws[4], aw2[4], aw3[4];
        float4 bv[4];
        #pragma unroll
        for (int of = 0; of < 4; ++of) {
            const unsigned short* wrow = wb + (size_t)(of * 16 + l15) * 96;
            aws[of] = *(const shortx8*)(wrow + quad * 8);
            aw2[of] = *(const shortx8*)(wrow + 32 + quad * 8);
            aw3[of] = *(const shortx8*)(wrow + 64 + quad * 8);
            bv[of]  = *(const float4*)(bias + of * 16 + quad * 4);
        }

        // acc -> Ul (bf16, swizzled): col=(m_loc*4+t), d=(jj&1)*16+l15, t=wj*2+(jj>>1)
        #pragma unroll
        for (int i = 0; i < 2; ++i)
            #pragma unroll
            for (int jj = 0; jj < 4; ++jj) {
                const int d = (jj & 1) * 16 + l15;
                const int tl = wj * 2 + (jj >> 1);
                #pragma unroll
                for (int reg = 0; reg < 4; ++reg) {
                    const int m_loc = i * 16 + quad * 4 + reg;
                    const int col = m_loc * 4 + tl;
                    const int byteoff = (wo * 128 + col) * 64
                                      + ((((d >> 3) ^ (col & 3))) << 4) + (d & 7) * 2;
                    *(unsigned short*)((char*)&Ul[0][0] + byteoff) = f2b(acc[i][jj][reg]);
                }
            }
        if (wj == 0 && l15 < 4) {   // sacc col l15 -> t = t0 + l15
            #pragma unroll
            for (int i = 0; i < 2; ++i)
                #pragma unroll
                for (int reg = 0; reg < 4; ++reg) {
                    const int m_loc = i * 16 + quad * 4 + reg;
                    Rl[wo * 128 + m_loc * 4 + l15] = 1.f / (sacc[i][reg] + 1.f);
                }
        }
        __syncthreads();

        // ---- MLP: each wave 2 col-frags x 4 o-frags x 3 sources ----
        #pragma unroll
        for (int cc = 0; cc < 2; ++cc) {
            const int cf = wave * 2 + cc;
            const int col = cf * 16 + l15;             // 0..127 = m_loc*4 + tl
            const float r0 = Rl[col], r1 = Rl[128 + col];
            const int sw = ((quad ^ (col & 3)) << 4);
            shortx8 bfF = *(const shortx8*)((const char*)&Fl[0] + col * 64 + sw);
            shortx8 b0  = *(const shortx8*)((const char*)&Ul[0][0] + col * 64 + sw);
            shortx8 b1  = *(const shortx8*)((const char*)&Ul[0][0] + (128 + col) * 64 + sw);
            float* yp = y + ((size_t)(b * 256 + m0 + (col >> 2))) * 8192 + t0 + (col & 3);
            #pragma unroll
            for (int of = 0; of < 4; ++of) {
                floatx4 z = {0.f, 0.f, 0.f, 0.f};
                floatx4 cw = __builtin_amdgcn_mfma_f32_16x16x32_bf16(aws[of], bfF, z, 0, 0, 0);
                floatx4 c2 = __builtin_amdgcn_mfma_f32_16x16x32_bf16(aw2[of], b0, z, 0, 0, 0);
                floatx4 c3 = __builtin_amdgcn_mfma_f32_16x16x32_bf16(aw3[of], b1, z, 0, 0, 0);
                #pragma unroll
                for (int reg = 0; reg < 4; ++reg) {
                    const int o = of * 16 + quad * 4 + reg;
                    float v = cw[reg] + r0 * c2[reg] + r1 * c3[reg]
                            + ((const float*)&bv[of])[reg];
                    yp[(size_t)o * 128] = v > 0.f ? v : 0.f;
                }
            }
        }
    }
    #undef STAGE
}

extern "C" void kernel_launch(void* const* d_in, const int* in_sizes, int n_in,
                              void* d_out, int out_size, void* d_ws, size_t ws_size,
                              hipStream_t stream) {
    const float* fc   = (const float*)d_in[0]; // [2,512,32,128]
    const float* ft   = (const float*)d_in[1]; // [2,256,32,128]
    const float* adj  = (const float*)d_in[2]; // [2,2,256,512]
    const float* mask = (const float*)d_in[3]; // [2,128,512]
    const float* W    = (const float*)d_in[4]; // [64,96]
    const float* bias = (const float*)d_in[5]; // [64]
    float* y = (float*)d_out;                  // [2,256,64,128]

    unsigned short* gt   = (unsigned short*)d_ws;            // [2][4224][512]
    unsigned short* adjb = gt   + (size_t)2 * 4224 * 512;    // [4][256][512]
    unsigned short* ftb  = adjb + (size_t)4 * 256 * 512;     // [2][256][128][32]
    unsigned short* wb   = ftb  + (size_t)2 * 256 * 128 * 32;// [64][96]
    // total ~13.9 MB

    k_prep <<<6785, 256, 0, stream>>>(fc, mask, adj, ft, W, gt, adjb, ftb, wb);
    k_fused<<<dim3(32, 8, 2), 256, 0, stream>>>(adjb, gt, ftb, wb, bias, y);
}

// Round 20
// 104.944 us; speedup vs baseline: 3.5765x; 3.5765x over previous
//
#include <hip/hip_runtime.h>
#include <cstdint>
#include <cstddef>

// Shapes: b=2, n=512, m=256, d=32, t=128, ORDER=2, C_OUT=64. All I/O fp32.
// Pipeline identical to round-10 verified build (absmax 0.03125), plus:
//   XCD-aware bid remap in k_fused (1-D grid 512):
//     bid = (i*8+mt)*16 + (g*2+b),  jt = g*4+i
//   -> XCD = bid%8 = (2g+b)%8 is constant across BOTH
//      (a) the 4 jt-siblings writing the same 64B y-line  (write-merge in L2)
//      (b) the 8 mt-blocks sharing a B tile               (read locality, as before)
//   Old mapping had XCD=jt%8: (b) held but (a) didn't -> measured 2.3x write amp
//   (WRITE_SIZE 37MB/rep vs y=16.8MB, m15 rocprof). All 512 blocks are co-resident
//   (2/CU), so sibling partial-line writes overlap in time and merge.

using shortx8 = __attribute__((ext_vector_type(8))) short;
using floatx4 = __attribute__((ext_vector_type(4))) float;

__device__ __forceinline__ unsigned short f2b(float f) {
    union { float f; unsigned int i; } v; v.f = f;
    unsigned int x = v.i;
    return (unsigned short)((x + 0x7FFFu + ((x >> 16) & 1u)) >> 16); // RNE
}
__device__ __forceinline__ void gl_lds16(const unsigned short* g, unsigned short* l) {
    __builtin_amdgcn_global_load_lds(
        (const __attribute__((address_space(1))) unsigned int*)g,
        (__attribute__((address_space(3))) unsigned int*)l, 16, 0, 0);
}

// ---------- prep: gt [0,4224) + adj [4224,4736) + ftb [4736,6784) + wb {6784} ----------
__global__ void k_prep(const float* __restrict__ fc, const float* __restrict__ mask,
                       const float* __restrict__ adj, const float* __restrict__ ft,
                       const float* __restrict__ W,
                       unsigned short* __restrict__ gt, unsigned short* __restrict__ adjb,
                       unsigned short* __restrict__ ftb, unsigned short* __restrict__ wb) {
    const int tid = threadIdx.x;
    __shared__ float wls[32][33];
    __shared__ unsigned short tls[32][34];
    const int x = blockIdx.x;

    if (x < 4224) {  // ---- gt ----
        const int jb = x % 132;
        const int rem = x / 132;
        const int nb = rem & 15, b = rem >> 4;
        const int n0 = nb * 32;
        const int r = tid >> 3, c4 = (tid & 7) * 4;
        if (jb >= 128) {
            const int t0 = (jb - 128) * 32;
            float4 mv = *(const float4*)(mask + ((size_t)b * 128 + t0 + r) * 512 + n0 + c4);
            ushort4 o;
            o.x = f2b(1.f - mv.x); o.y = f2b(1.f - mv.y);
            o.z = f2b(1.f - mv.z); o.w = f2b(1.f - mv.w);
            *(ushort4*)(gt + ((size_t)b * 4224 + 4096 + t0 + r) * 512 + n0 + c4) = o;
            return;
        }
        const int j0 = jb * 32;
        const int t0 = j0 & 127;
        {
            float4 mv = *(const float4*)(mask + ((size_t)b * 128 + t0 + r) * 512 + n0 + c4);
            wls[r][c4 + 0] = 1.f - mv.x; wls[r][c4 + 1] = 1.f - mv.y;
            wls[r][c4 + 2] = 1.f - mv.z; wls[r][c4 + 3] = 1.f - mv.w;
        }
        float4 fv = *(const float4*)(fc + ((size_t)b * 512 + n0 + r) * 4096 + j0 + c4);
        __syncthreads();
        tls[c4 + 0][r] = f2b(fv.x * wls[c4 + 0][r]);
        tls[c4 + 1][r] = f2b(fv.y * wls[c4 + 1][r]);
        tls[c4 + 2][r] = f2b(fv.z * wls[c4 + 2][r]);
        tls[c4 + 3][r] = f2b(fv.w * wls[c4 + 3][r]);
        __syncthreads();
        ushort4 o;
        o.x = tls[r][c4 + 0]; o.y = tls[r][c4 + 1];
        o.z = tls[r][c4 + 2]; o.w = tls[r][c4 + 3];
        *(ushort4*)(gt + ((size_t)b * 4224 + j0 + r) * 512 + n0 + c4) = o;
    } else if (x < 4736) {  // ---- adj ----
        int i4 = ((x - 4224) * 256 + tid) * 4;
        float4 v = *(const float4*)(adj + i4);
        ushort4 o;
        o.x = f2b(v.x); o.y = f2b(v.y); o.z = f2b(v.z); o.w = f2b(v.w);
        *(ushort4*)(adjb + i4) = o;
    } else if (x < 6784) {  // ---- ftb: [m][d][t] -> [m][t][d] bf16 ----
        const int fb = x - 4736;
        const int b = fb >> 10, rem = fb & 1023;
        const int m = rem >> 2, tb = rem & 3;
        const int r = tid >> 3, c4 = (tid & 7) * 4;
        float4 fv = *(const float4*)(ft + (((size_t)(b * 256 + m)) * 32 + r) * 128 + tb * 32 + c4);
        tls[c4 + 0][r] = f2b(fv.x); tls[c4 + 1][r] = f2b(fv.y);
        tls[c4 + 2][r] = f2b(fv.z); tls[c4 + 3][r] = f2b(fv.w);
        __syncthreads();
        ushort4 o;
        o.x = tls[r][c4 + 0]; o.y = tls[r][c4 + 1];
        o.z = tls[r][c4 + 2]; o.w = tls[r][c4 + 3];
        *(ushort4*)(ftb + (((size_t)(b * 256 + m)) * 128 + tb * 32 + r) * 32 + c4) = o;
    } else {  // ---- wb: fold W1+W2+W3, bf16 ----
        if (tid < 64) {
            for (int c = 0; c < 32; ++c) {
                float w1 = W[tid * 96 + c];
                float w2 = W[tid * 96 + 32 + c];
                float w3 = W[tid * 96 + 64 + c];
                wb[tid * 96 + c]      = f2b(w1 + w2 + w3);
                wb[tid * 96 + 32 + c] = f2b(w2);
                wb[tid * 96 + 64 + c] = f2b(w3);
            }
        }
    }
}

// ---------- fused GEMM(2 orders + s) + MLP, grid 512 (XCD-remapped), 256 thr ----------
__launch_bounds__(256, 2)
__global__ void k_fused(const unsigned short* __restrict__ adjb,
                        const unsigned short* __restrict__ gt,
                        const unsigned short* __restrict__ ftb,
                        const unsigned short* __restrict__ wb,
                        const float* __restrict__ bias, float* __restrict__ y) {
    // XCD-aware decode: bid = (i*8+mt)*16 + (g*2+b); jt = g*4+i
    const int bid = blockIdx.x;
    const int lo  = bid & 15;
    const int g   = lo >> 1, b = lo & 1;
    const int hi  = bid >> 4;
    const int jt  = g * 4 + (hi >> 3);
    const int mt  = hi & 7;
    const int t0 = jt * 4, m0 = mt * 32;
    const int tid = threadIdx.x;
    const int wave = tid >> 6, lane = tid & 63;
    const int l15 = lane & 15, quad = lane >> 4;
    const int wo = wave & 1, wj = wave >> 1;   // order-half, j-half
    const int srow = lane >> 3;                // 0..7 row in 8-row staging chunk
    const int ksw = (((lane & 7) ^ srow) * 8); // pre-swizzled k-offset (T2, rule #21)

    __shared__ __align__(16) unsigned short Al[2][2][32 * 64];  // [buf][ord] 16 KB
    __shared__ __align__(16) unsigned short Bl[2][144 * 64];    // 128 j + 16 s-dup, 36 KB
    __shared__ __align__(16) unsigned short Fl[128 * 32];       // ft tile [col][d], 8 KB
    __shared__ __align__(16) unsigned short Ul[2][128 * 32];    // u tiles [ord][col][d], 16 KB
    __shared__ float Rl[2 * 128];                               // 1/(s+1), 1 KB

    const unsigned short* gtb = gt + (size_t)b * 4224 * 512;

    // B tile-local row r -> gt row: j = (r&31)*128 + t0 + (r>>5)   (d=r&31, t=t0+(r>>5))
    #define STAGE(buf, k0)                                                            \
        _Pragma("unroll")                                                             \
        for (int aa = 0; aa < 2; ++aa) {                                              \
            const int a = wave * 2 + aa;           /* 0..7 */                         \
            const int ord = a >> 2, ch = a & 3;                                       \
            const int row = ch * 8 + srow;                                            \
            gl_lds16(adjb + ((size_t)((b * 2 + ord) * 256 + m0 + row)) * 512          \
                          + (k0) + ksw,                                               \
                     &Al[buf][ord][ch * 512]);                                        \
        }                                                                             \
        _Pragma("unroll")                                                             \
        for (int rr = 0; rr < 4; ++rr) {                                              \
            const int ch = wave * 4 + rr;          /* 0..15 */                        \
            const int row = ch * 8 + srow;                                            \
            const int jrow = (row & 31) * 128 + t0 + (row >> 5);                      \
            gl_lds16(gtb + (size_t)jrow * 512 + (k0) + ksw, &Bl[buf][ch * 512]);      \
        }                                                                             \
        if (wave < 2)                                                                 \
            gl_lds16(gtb + (size_t)(4096 + t0 + (srow & 3)) * 512 + (k0) + ksw,       \
                     &Bl[buf][128 * 64 + wave * 512]);

    floatx4 acc[2][4], sacc[2];
    #pragma unroll
    for (int i = 0; i < 2; ++i) {
        sacc[i] = (floatx4){0.f, 0.f, 0.f, 0.f};
        #pragma unroll
        for (int j = 0; j < 4; ++j) acc[i][j] = (floatx4){0.f, 0.f, 0.f, 0.f};
    }

    STAGE(0, 0)
    // stage ft tile once (swizzled source -> linear LDS); consumed after epilogue barrier
    #pragma unroll
    for (int cc = 0; cc < 2; ++cc) {
        const int c = wave * 2 + cc;               // 0..7
        const int col = c * 16 + (lane >> 2), qs = lane & 3;
        gl_lds16(ftb + (((size_t)(b * 256 + m0 + (col >> 2))) * 128 + t0 + (col & 3)) * 32
                     + ((qs ^ (col & 3)) * 8),
                 &Fl[c * 512]);
    }

    int cur = 0;
    for (int it = 0; it < 8; ++it) {
        __syncthreads();                  // buf[cur] ready (compiler drains vmcnt)
        if (it < 7) { STAGE(cur ^ 1, (it + 1) * 64) }
        #pragma unroll
        for (int ks = 0; ks < 2; ++ks) {
            const int swz = (((ks * 4 + quad) ^ (l15 & 7)) << 4);
            shortx8 af[2], bf[4];
            #pragma unroll
            for (int i = 0; i < 2; ++i)
                af[i] = *(const shortx8*)((const char*)&Al[cur][wo][0]
                                          + (i * 16 + l15) * 128 + swz);
            #pragma unroll
            for (int jj = 0; jj < 4; ++jj)
                bf[jj] = *(const shortx8*)((const char*)&Bl[cur][0]
                                           + (wj * 64 + jj * 16 + l15) * 128 + swz);
            #pragma unroll
            for (int i = 0; i < 2; ++i)
                #pragma unroll
                for (int jj = 0; jj < 4; ++jj)
                    acc[i][jj] = __builtin_amdgcn_mfma_f32_16x16x32_bf16(af[i], bf[jj],
                                                                         acc[i][jj], 0, 0, 0);
            if (wj == 0) {   // s-rows: every col a valid duplicate (t = t0 + (l15&3))
                shortx8 sf = *(const shortx8*)((const char*)&Bl[cur][0]
                                               + (128 + l15) * 128 + swz);
                #pragma unroll
                for (int i = 0; i < 2; ++i)
                    sacc[i] = __builtin_amdgcn_mfma_f32_16x16x32_bf16(af[i], sf,
                                                                      sacc[i], 0, 0, 0);
            }
        }
        cur ^= 1;
    }
    #undef STAGE

    // ---- epilogue: load W frags (global, hides under LDS writes) ----
    shortx8 aws[4], aw2[4], aw3[4];
    float4 bv[4];
    #pragma unroll
    for (int of = 0; of < 4; ++of) {
        const unsigned short* wrow = wb + (size_t)(of * 16 + l15) * 96;
        aws[of] = *(const shortx8*)(wrow + quad * 8);
        aw2[of] = *(const shortx8*)(wrow + 32 + quad * 8);
        aw3[of] = *(const shortx8*)(wrow + 64 + quad * 8);
        bv[of]  = *(const float4*)(bias + of * 16 + quad * 4);
    }

    // acc -> Ul (bf16, swizzled): col=(m_loc*4+t), d=(jj&1)*16+l15, t=wj*2+(jj>>1)
    #pragma unroll
    for (int i = 0; i < 2; ++i)
        #pragma unroll
        for (int jj = 0; jj < 4; ++jj) {
            const int d = (jj & 1) * 16 + l15;
            const int tl = wj * 2 + (jj >> 1);
            #pragma unroll
            for (int reg = 0; reg < 4; ++reg) {
                const int m_loc = i * 16 + quad * 4 + reg;
                const int col = m_loc * 4 + tl;
                const int byteoff = (wo * 128 + col) * 64
                                  + ((((d >> 3) ^ (col & 3))) << 4) + (d & 7) * 2;
                *(unsigned short*)((char*)&Ul[0][0] + byteoff) = f2b(acc[i][jj][reg]);
            }
        }
    if (wj == 0 && l15 < 4) {   // sacc col l15 -> t = t0 + l15
        #pragma unroll
        for (int i = 0; i < 2; ++i)
            #pragma unroll
            for (int reg = 0; reg < 4; ++reg) {
                const int m_loc = i * 16 + quad * 4 + reg;
                Rl[wo * 128 + m_loc * 4 + l15] = 1.f / (sacc[i][reg] + 1.f);
            }
    }
    __syncthreads();

    // ---- MLP: each wave 2 col-frags x 4 o-frags x 3 sources ----
    #pragma unroll
    for (int cc = 0; cc < 2; ++cc) {
        const int cf = wave * 2 + cc;
        const int col = cf * 16 + l15;             // 0..127 = m_loc*4 + tl
        const float r0 = Rl[col], r1 = Rl[128 + col];
        const int sw = ((quad ^ (col & 3)) << 4);
        shortx8 bfF = *(const shortx8*)((const char*)&Fl[0] + col * 64 + sw);
        shortx8 b0  = *(const shortx8*)((const char*)&Ul[0][0] + col * 64 + sw);
        shortx8 b1  = *(const shortx8*)((const char*)&Ul[0][0] + (128 + col) * 64 + sw);
        float* yp = y + ((size_t)(b * 256 + m0 + (col >> 2))) * 8192 + t0 + (col & 3);
        #pragma unroll
        for (int of = 0; of < 4; ++of) {
            floatx4 z = {0.f, 0.f, 0.f, 0.f};
            floatx4 cw = __builtin_amdgcn_mfma_f32_16x16x32_bf16(aws[of], bfF, z, 0, 0, 0);
            floatx4 c2 = __builtin_amdgcn_mfma_f32_16x16x32_bf16(aw2[of], b0, z, 0, 0, 0);
            floatx4 c3 = __builtin_amdgcn_mfma_f32_16x16x32_bf16(aw3[of], b1, z, 0, 0, 0);
            #pragma unroll
            for (int reg = 0; reg < 4; ++reg) {
                const int o = of * 16 + quad * 4 + reg;
                float v = cw[reg] + r0 * c2[reg] + r1 * c3[reg]
                        + ((const float*)&bv[of])[reg];
                yp[(size_t)o * 128] = v > 0.f ? v : 0.f;
            }
        }
    }
}

extern "C" void kernel_launch(void* const* d_in, const int* in_sizes, int n_in,
                              void* d_out, int out_size, void* d_ws, size_t ws_size,
                              hipStream_t stream) {
    const float* fc   = (const float*)d_in[0]; // [2,512,32,128]
    const float* ft   = (const float*)d_in[1]; // [2,256,32,128]
    const float* adj  = (const float*)d_in[2]; // [2,2,256,512]
    const float* mask = (const float*)d_in[3]; // [2,128,512]
    const float* W    = (const float*)d_in[4]; // [64,96]
    const float* bias = (const float*)d_in[5]; // [64]
    float* y = (float*)d_out;                  // [2,256,64,128]

    unsigned short* gt   = (unsigned short*)d_ws;            // [2][4224][512]
    unsigned short* adjb = gt   + (size_t)2 * 4224 * 512;    // [4][256][512]
    unsigned short* ftb  = adjb + (size_t)4 * 256 * 512;     // [2][256][128][32]
    unsigned short* wb   = ftb  + (size_t)2 * 256 * 128 * 32;// [64][96]
    // total ~13.9 MB

    k_prep <<<6785, 256, 0, stream>>>(fc, mask, adj, ft, W, gt, adjb, ftb, wb);
    k_fused<<<512, 256, 0, stream>>>(adjb, gt, ftb, wb, bias, y);
}